// Round 2
// baseline (150.680 us; speedup 1.0000x reference)
//
#include <hip/hip_runtime.h>
#include <hip/hip_bf16.h>

typedef short short8 __attribute__((ext_vector_type(8)));
typedef float floatx4 __attribute__((ext_vector_type(4)));
typedef float float2v __attribute__((ext_vector_type(2)));
typedef unsigned uint4v __attribute__((ext_vector_type(4)));

#define NN 2000      // nodes
#define NE 40000     // edges
#define NB 4         // batch
#define T_IN 34
#define TP 32        // output time steps
#define NBT (NB * TP)         // 128 bt slices
#define CAP 96                // padded-CSR capacity (max in-deg ~45 for Poisson(20))
#define NEB 157               // edge-fill blocks (40000/256 rounded up)

// ws layout (float offsets):
//  deg:     [0, 2048)            float (memset 0)
//  cursor:  [2048, 4096)         int   (memset 0)
//  pcsr:    [4096, 388096)       int2{src, bits(ew)} x (2000*96)
//  h2:      [388096 ..)          dword-packed bf16 pairs, 2000*128*16 dwords = 16.4 MB
//  h2 dword k of slice (n,bt): low16 = bf16(h[c=k]), high16 = bf16(h[c=k+16])

// ---------- bf16 helpers ----------
__device__ inline unsigned short f2bf(float x) {        // RNE (for h2 store)
    unsigned int u = __float_as_uint(x);
    u = u + 0x7fff + ((u >> 16) & 1);
    return (unsigned short)(u >> 16);
}
// Truncation split of 2 floats -> packed hi dword + packed lo dword.
// hi = x & 0xffff0000 (exact bf16 trunc); lo = x - hi (EXACT in f32).
__device__ inline void splitPair(float x0, float x1, unsigned& hi, unsigned& lo) {
    unsigned u0 = __float_as_uint(x0), u1 = __float_as_uint(x1);
    hi = __builtin_amdgcn_perm(u1, u0, 0x07060302u);   // [top16(x1), top16(x0)]
    float r0 = x0 - __uint_as_float(u0 & 0xffff0000u);
    float r1 = x1 - __uint_as_float(u1 & 0xffff0000u);
    lo = __builtin_amdgcn_perm(__float_as_uint(r1), __float_as_uint(r0), 0x07060302u);
}
__device__ inline void splitA8(const float* v, short8& hi, short8& lo) {
    union { unsigned u[4]; short8 s; } H, L;
#pragma unroll
    for (int j = 0; j < 4; ++j) {
        unsigned h_, l_;
        splitPair(v[2 * j], v[2 * j + 1], h_, l_);
        H.u[j] = h_; L.u[j] = l_;
    }
    hi = H.s; lo = L.s;
}

// ---- conv (t-chained) + deg + padded-CSR fill ----
// Edge blocks first (blockIdx < NEB): degree accumulation + slot fill.
// Conv waves: unit = (b, 16-node tile, 8-output t-block). Ring of 3 input
// slices (invariant: slice t0+m lives in slot m%3): 10 loads per 8 outputs
// (1.25x fetch vs 2x before), each slice trunc-split exactly once.
__global__ __launch_bounds__(256) void conv_deg_kernel(
        const float* __restrict__ x,
        const float* __restrict__ w1, const float* __restrict__ b1,
        const float* __restrict__ w2, const float* __restrict__ b2,
        unsigned* __restrict__ h2,
        const int* __restrict__ row, const int* __restrict__ col,
        const float* __restrict__ ew,
        float* __restrict__ deg, int* __restrict__ cursor,
        int2* __restrict__ pcsr) {
    if (blockIdx.x < NEB) {
        int e = blockIdx.x * 256 + threadIdx.x;
        if (e < NE) {
            int c = col[e], r = row[e];
            float w = ew[e];
            atomicAdd(&deg[c], w);
            int slot = atomicAdd(&cursor[c], 1);
            if (slot < CAP) pcsr[c * CAP + slot] = make_int2(r, __float_as_int(w));
        }
        return;
    }

    int l = threadIdx.x & 63;
    int w = threadIdx.x >> 6;
    int colL = l & 15, q = l >> 4;

    // B fragments [gate][dc-half][tap], trunc-split hi/lo. Once per wave.
    short8 Whi[2][2][2], Wlo[2][2][2];
#pragma unroll
    for (int g = 0; g < 2; ++g) {
        const float* wp = g ? w2 : w1;
#pragma unroll
        for (int d = 0; d < 2; ++d)
#pragma unroll
        for (int tap = 0; tap < 2; ++tap) {
            float wv[8];
#pragma unroll
            for (int j = 0; j < 8; ++j)
                wv[j] = wp[(d * 16 + colL) * 64 + (q * 8 + j) * 2 + tap];
            splitA8(wv, Whi[g][d][tap], Wlo[g][d][tap]);
        }
    }
    float bias[2][2] = { { b1[colL], b1[colL + 16] }, { b2[colL], b2[colL + 16] } };

    int cb = blockIdx.x - NEB;           // 0..499
    int ntile = cb % 125;
    int b_ = cb / 125;                   // 0..3
    int tb = w;                          // 0..3 -> t-block of 8 outputs
    int n0 = ntile * 16;
    int t0 = tb * 8;

    const float* xw = x + (((size_t)b_ * T_IN * NN) + n0 + colL) * 32 + q * 8;
    auto LD = [&](int t, float* vdst) {
        const float* p = xw + (size_t)t * (NN * 32);
        *(float4*)vdst       = *(const float4*)p;
        *(float4*)(vdst + 4) = *(const float4*)(p + 4);
    };

    float v[3][8];
    short8 shi[3], slo[3];
    LD(t0, v[0]); LD(t0 + 1, v[1]); LD(t0 + 2, v[2]);
    splitA8(v[0], shi[0], slo[0]);
    splitA8(v[1], shi[1], slo[1]);

#pragma unroll
    for (int j = 0; j < 8; ++j) {
        const int c0 = j % 3;            // slice t0+j   (tap 0) — split already done
        const int c2 = (j + 2) % 3;      // slice t0+j+2 (tap 1) — split here
        splitA8(v[c2], shi[c2], slo[c2]);
        // prefetch slice t0+j+3 into slot (j+3)%3 == c0; the raw floats of
        // slice t0+j are dead (its split shi[c0]/slo[c0] is materialized).
        if (j < 7) LD(t0 + j + 3, v[c0]);

        floatx4 acc[2][2];
#pragma unroll
        for (int g = 0; g < 2; ++g)
#pragma unroll
        for (int d = 0; d < 2; ++d) {
            float bv = bias[g][d];
            floatx4 a = { bv, bv, bv, bv };
            a = __builtin_amdgcn_mfma_f32_16x16x32_bf16(shi[c0], Whi[g][d][0], a, 0, 0, 0);
            a = __builtin_amdgcn_mfma_f32_16x16x32_bf16(shi[c2], Whi[g][d][1], a, 0, 0, 0);
            a = __builtin_amdgcn_mfma_f32_16x16x32_bf16(slo[c0], Whi[g][d][0], a, 0, 0, 0);
            a = __builtin_amdgcn_mfma_f32_16x16x32_bf16(slo[c2], Whi[g][d][1], a, 0, 0, 0);
            a = __builtin_amdgcn_mfma_f32_16x16x32_bf16(shi[c0], Wlo[g][d][0], a, 0, 0, 0);
            a = __builtin_amdgcn_mfma_f32_16x16x32_bf16(shi[c2], Wlo[g][d][1], a, 0, 0, 0);
            acc[g][d] = a;
        }

        int bt = b_ * TP + t0 + j;
#pragma unroll
        for (int r = 0; r < 4; ++r) {
            float g10 = acc[0][0][r], g20 = acc[1][0][r];
            float g11 = acc[0][1][r], g21 = acc[1][1][r];
            float e20 = __expf(2.0f * g10);
            float th0 = (e20 - 1.0f) / (e20 + 1.0f);
            float sg0 = 1.0f / (1.0f + __expf(-g20));
            float e21 = __expf(2.0f * g11);
            float th1 = (e21 - 1.0f) / (e21 + 1.0f);
            float sg1 = 1.0f / (1.0f + __expf(-g21));
            unsigned pk = (unsigned)f2bf(th0 * sg0) | ((unsigned)f2bf(th1 * sg1) << 16);
            int n = n0 + q * 4 + r;
            h2[(n * NBT + bt) * 16 + colL] = pk;
        }
    }
}

// packed-pair accumulate: dword j holds bf16(c=k_j) | bf16(c=k_j+16)<<16;
// a2[j].x accumulates c=k_j, a2[j].y accumulates c=k_j+16. v_pk_fma_f32
// runs both fmas in one double-rate instruction.
__device__ inline void acc8(float2v* a2, uint4v u, float2v nr2) {
#pragma unroll
    for (int j = 0; j < 4; ++j) {
        float2v vv;
        vv.x = __uint_as_float(u[j] << 16);
        vv.y = __uint_as_float(u[j] & 0xffff0000u);
        asm("v_pk_fma_f32 %0, %1, %2, %0" : "+v"(a2[j]) : "v"(vv), "v"(nr2));
    }
}

// ---------- fused aggregation + gcn ----------
// Wave = (node, chunk-pair of 16 bt). Per edge: wave-uniform slot load
// {src, ew}, norm computed on the fly from completed deg, ONE coalesced
// 1KB gather. blockIdx%8 XCD swizzle keeps the 2MB h2 slice L2-resident.
__global__ __launch_bounds__(256) void agg_gcn_kernel(
        const unsigned* __restrict__ h2,
        const float* __restrict__ deg, const int* __restrict__ cursor,
        const int2* __restrict__ pcsr,
        const float* __restrict__ gw, const float* __restrict__ gb,
        float* __restrict__ out) {
    __shared__ float st[64 * 36];   // 4 tiles of 16x32, stride 36
    int l = threadIdx.x & 63;
    int wv = threadIdx.x >> 6;
    int b = blockIdx.x;
    int cp = b & 7;                      // chunk-pair (16 bt) == XCD slice
    int n = (b >> 3) * 4 + wv;           // 0..1999
    int colL = l & 15, q = l >> 4;

    // gcn B fragments (trunc split) — latency hidden under gather loop
    short8 Bhi[2], Blo[2];
#pragma unroll
    for (int d = 0; d < 2; ++d) {
        float wv8[8];
#pragma unroll
        for (int j = 0; j < 8; ++j)
            wv8[j] = gw[(q * 8 + j) * 32 + d * 16 + colL];
        splitA8(wv8, Bhi[d], Blo[d]);
    }
    float gb0 = gb[colL], gb1 = gb[colL + 16];

    const unsigned* base = h2 + cp * 256 + l * 4;   // lane: bt=l>>2, k=(l&3)*4
    float dn = rsqrtf(deg[n] + 1.0f);
    float2v a2[4] = { {0,0}, {0,0}, {0,0}, {0,0} };
    {
        float w0 = dn * dn;                  // self-loop norm
        uint4v sv = *(const uint4v*)(base + (size_t)n * 2048);
        acc8(a2, sv, (float2v){ w0, w0 });
    }
    int cnt = cursor[n]; if (cnt > CAP) cnt = CAP;
    const int2* slots = pcsr + n * CAP;
    int i = 0;
    for (; i + 8 <= cnt; i += 8) {
        int2 e0 = slots[i],     e1 = slots[i + 1], e2 = slots[i + 2], e3 = slots[i + 3];
        int2 e4 = slots[i + 4], e5 = slots[i + 5], e6 = slots[i + 6], e7 = slots[i + 7];
        float n0 = rsqrtf(deg[e0.x] + 1.0f) * __int_as_float(e0.y) * dn;
        float n1 = rsqrtf(deg[e1.x] + 1.0f) * __int_as_float(e1.y) * dn;
        float n2 = rsqrtf(deg[e2.x] + 1.0f) * __int_as_float(e2.y) * dn;
        float n3 = rsqrtf(deg[e3.x] + 1.0f) * __int_as_float(e3.y) * dn;
        float n4 = rsqrtf(deg[e4.x] + 1.0f) * __int_as_float(e4.y) * dn;
        float n5 = rsqrtf(deg[e5.x] + 1.0f) * __int_as_float(e5.y) * dn;
        float n6 = rsqrtf(deg[e6.x] + 1.0f) * __int_as_float(e6.y) * dn;
        float n7 = rsqrtf(deg[e7.x] + 1.0f) * __int_as_float(e7.y) * dn;
        uint4v v0 = *(const uint4v*)(base + (size_t)e0.x * 2048);
        uint4v v1 = *(const uint4v*)(base + (size_t)e1.x * 2048);
        uint4v v2 = *(const uint4v*)(base + (size_t)e2.x * 2048);
        uint4v v3 = *(const uint4v*)(base + (size_t)e3.x * 2048);
        uint4v v4 = *(const uint4v*)(base + (size_t)e4.x * 2048);
        uint4v v5 = *(const uint4v*)(base + (size_t)e5.x * 2048);
        uint4v v6 = *(const uint4v*)(base + (size_t)e6.x * 2048);
        uint4v v7 = *(const uint4v*)(base + (size_t)e7.x * 2048);
        acc8(a2, v0, (float2v){n0, n0}); acc8(a2, v1, (float2v){n1, n1});
        acc8(a2, v2, (float2v){n2, n2}); acc8(a2, v3, (float2v){n3, n3});
        acc8(a2, v4, (float2v){n4, n4}); acc8(a2, v5, (float2v){n5, n5});
        acc8(a2, v6, (float2v){n6, n6}); acc8(a2, v7, (float2v){n7, n7});
    }
    for (; i + 4 <= cnt; i += 4) {
        int2 e0 = slots[i], e1 = slots[i + 1], e2 = slots[i + 2], e3 = slots[i + 3];
        float n0 = rsqrtf(deg[e0.x] + 1.0f) * __int_as_float(e0.y) * dn;
        float n1 = rsqrtf(deg[e1.x] + 1.0f) * __int_as_float(e1.y) * dn;
        float n2 = rsqrtf(deg[e2.x] + 1.0f) * __int_as_float(e2.y) * dn;
        float n3 = rsqrtf(deg[e3.x] + 1.0f) * __int_as_float(e3.y) * dn;
        uint4v v0 = *(const uint4v*)(base + (size_t)e0.x * 2048);
        uint4v v1 = *(const uint4v*)(base + (size_t)e1.x * 2048);
        uint4v v2 = *(const uint4v*)(base + (size_t)e2.x * 2048);
        uint4v v3 = *(const uint4v*)(base + (size_t)e3.x * 2048);
        acc8(a2, v0, (float2v){n0, n0}); acc8(a2, v1, (float2v){n1, n1});
        acc8(a2, v2, (float2v){n2, n2}); acc8(a2, v3, (float2v){n3, n3});
    }
    for (; i < cnt; ++i) {
        int2 e0 = slots[i];
        float n0 = rsqrtf(deg[e0.x] + 1.0f) * __int_as_float(e0.y) * dn;
        uint4v v0 = *(const uint4v*)(base + (size_t)e0.x * 2048);
        acc8(a2, v0, (float2v){n0, n0});
    }

    // stage: lane l holds (bt_local = l>>2, c = (l&3)*4+j and +16)
    float* dst = &st[(wv * 16 + (l >> 2)) * 36 + (l & 3) * 4];
    *(float4*)dst        = make_float4(a2[0].x, a2[1].x, a2[2].x, a2[3].x);
    *(float4*)(dst + 16) = make_float4(a2[0].y, a2[1].y, a2[2].y, a2[3].y);
    __syncthreads();

    // each wave MFMAs its own node's 16(bt) x 32(c) tile
    float av[8];
    const float* ap = &st[(wv * 16 + colL) * 36 + q * 8];
    *(float4*)av       = *(const float4*)ap;
    *(float4*)(av + 4) = *(const float4*)(ap + 4);
    short8 Ahi, Alo;
    splitA8(av, Ahi, Alo);
    floatx4 z = { 0.f, 0.f, 0.f, 0.f };
    floatx4 acc0 = z, acc1 = z;
    acc0 = __builtin_amdgcn_mfma_f32_16x16x32_bf16(Ahi, Bhi[0], acc0, 0, 0, 0);
    acc0 = __builtin_amdgcn_mfma_f32_16x16x32_bf16(Alo, Bhi[0], acc0, 0, 0, 0);
    acc0 = __builtin_amdgcn_mfma_f32_16x16x32_bf16(Ahi, Blo[0], acc0, 0, 0, 0);
    acc1 = __builtin_amdgcn_mfma_f32_16x16x32_bf16(Ahi, Bhi[1], acc1, 0, 0, 0);
    acc1 = __builtin_amdgcn_mfma_f32_16x16x32_bf16(Alo, Bhi[1], acc1, 0, 0, 0);
    acc1 = __builtin_amdgcn_mfma_f32_16x16x32_bf16(Ahi, Blo[1], acc1, 0, 0, 0);
#pragma unroll
    for (int r = 0; r < 4; ++r) {
        int btl = q * 4 + r;
        size_t o = ((size_t)(cp * 16 + btl) * NN + n) << 5;
        out[o + colL]      = acc0[r] + gb0;
        out[o + colL + 16] = acc1[r] + gb1;
    }
}

extern "C" void kernel_launch(void* const* d_in, const int* in_sizes, int n_in,
                              void* d_out, int out_size, void* d_ws, size_t ws_size,
                              hipStream_t stream) {
    const float* x   = (const float*)d_in[0];
    const int*   ei  = (const int*)d_in[1];
    const float* ew  = (const float*)d_in[2];
    const float* g1w = (const float*)d_in[3];
    const float* g1b = (const float*)d_in[4];
    const float* g2w = (const float*)d_in[5];
    const float* g2b = (const float*)d_in[6];
    const float* gcw = (const float*)d_in[7];
    const float* gcb = (const float*)d_in[8];
    float* out = (float*)d_out;

    float* wsf      = (float*)d_ws;
    float* deg      = wsf;
    int*   cursor   = (int*)(wsf + 2048);
    int2*  pcsr     = (int2*)(wsf + 4096);
    unsigned* h2    = (unsigned*)(wsf + 388096);

    const int* row = ei;
    const int* col = ei + NE;

    hipMemsetAsync(wsf, 0, 4096 * sizeof(float), stream);   // deg + cursor
    hipLaunchKernelGGL(conv_deg_kernel, dim3(NEB + 500), dim3(256), 0, stream,
                       x, g1w, g1b, g2w, g2b, h2, row, col, ew,
                       deg, cursor, pcsr);
    hipLaunchKernelGGL(agg_gcn_kernel, dim3(4000), dim3(256), 0, stream,
                       h2, deg, cursor, pcsr, gcw, gcb, out);
}